// Round 2
// baseline (377.239 us; speedup 1.0000x reference)
//
#include <hip/hip_runtime.h>

// ---------------------------------------------------------------------------
// ContrastiveLoss: loss = mean_i [ 0.5*(LSE_row_i + LSE_col_i) - diag_i ]
// over logits = normalize(img) @ normalize(txt)^T / 0.07, N=8192, D=1024.
// |logit| <= 14.29 -> exp() safe in fp32, no max subtraction needed.
//
// R1: MFMA-ordered LDS staging. global_load_lds writes to base + lane*16, so
// we pick the global chunk each lane fetches such that LDS holds each
// 16-row x 32-k tile in exact MFMA A/B fragment order. Fragment reads become
// contiguous (addr = tile*1KB + lane*16) -> zero bank conflicts.
// ---------------------------------------------------------------------------

#define BM 128
#define BN 128
#define BK 32

typedef __bf16 bf16x8 __attribute__((ext_vector_type(8)));
typedef float  floatx4 __attribute__((ext_vector_type(4)));

__device__ __forceinline__ unsigned short f2bf(float f) {
    unsigned int u = __float_as_uint(f);
    u += 0x7fffu + ((u >> 16) & 1u);   // round-to-nearest-even
    return (unsigned short)(u >> 16);
}

__device__ __forceinline__ void gload_lds16(const unsigned short* g, unsigned short* lds) {
    __builtin_amdgcn_global_load_lds(
        (const __attribute__((address_space(1))) void*)g,
        (__attribute__((address_space(3))) void*)lds,
        16, 0, 0);
}

// ---- Kernel 1: row L2-normalize (clamp at eps) and cast fp32 -> bf16 -------
// Handles both tensors: blocks [0,N) -> img, [N,2N) -> txt.
__global__ __launch_bounds__(256)
void normalize_bf16(const float* __restrict__ img, const float* __restrict__ txt,
                    unsigned short* __restrict__ oimg, unsigned short* __restrict__ otxt,
                    int D, int N) {
    const int b = blockIdx.x;
    const float* in = (b < N) ? img : txt;
    unsigned short* out = (b < N) ? oimg : otxt;
    const int row = (b < N) ? b : b - N;
    const int t = threadIdx.x;
    const float4 v = ((const float4*)(in + (size_t)row * D))[t];
    float ss = v.x * v.x + v.y * v.y + v.z * v.z + v.w * v.w;
    #pragma unroll
    for (int o = 1; o < 64; o <<= 1) ss += __shfl_xor(ss, o);
    __shared__ float wss[4];
    if ((t & 63) == 0) wss[t >> 6] = ss;
    __syncthreads();
    const float tot = wss[0] + wss[1] + wss[2] + wss[3];
    const float inv = 1.0f / fmaxf(sqrtf(tot), 1e-8f);
    ushort4 o4;
    o4.x = f2bf(v.x * inv);
    o4.y = f2bf(v.y * inv);
    o4.z = f2bf(v.z * inv);
    o4.w = f2bf(v.w * inv);
    *(ushort4*)(out + (size_t)row * D + t * 4) = o4;
}

// ---- Kernel 2: 128x128-tile NT GEMM + fused exp / row-col sums / diag ------
__global__ __launch_bounds__(256)
void gemm_exp_kernel(const unsigned short* __restrict__ A,   // img_n [N][K] bf16
                     const unsigned short* __restrict__ B,   // txt_n [N][K] bf16
                     float* __restrict__ rowsum, float* __restrict__ colsum,
                     float* __restrict__ diag, int K, float scale) {
    // MFMA-ordered layout: 8 tiles of (16 rows x 32 k) = 1KB each.
    // Within tile, chunk position p (16B): row = p & 15, kblock = p >> 4.
    __shared__ unsigned short As[BM * BK];   // 8 KB
    __shared__ unsigned short Bs[BN * BK];   // 8 KB

    const int bm = blockIdx.x, bn = blockIdx.y;
    const int tid = threadIdx.x;
    const int lane = tid & 63;
    const int wave = tid >> 6;
    const int quad = lane >> 4;
    const int lanelo = lane & 15;
    const int wrow = (wave >> 1) * 64;   // wave quadrant within 128x128
    const int wcol = (wave & 1) * 64;

    floatx4 acc[4][4] = {};

    // Staging: wave w covers tiles 2w (rows 32w..32w+15) and 2w+1 (+16).
    // Lane l fetches row (32w + (l&15)), k-bytes block (l>>4).
    const int kb = lane >> 4;                 // 0..3 (8 bf16 each)
    const int srow = wave * 32 + lanelo;      // tile-local staging row
    unsigned short* dstA = As + (wave * 128 + lane) * 8;  // tile 2w, pos=lane
    unsigned short* dstB = Bs + (wave * 128 + lane) * 8;

    const unsigned short* pa0 = A + (size_t)bm * BM * K + (size_t)srow * K + kb * 8;
    const unsigned short* pa1 = pa0 + (size_t)16 * K;
    const unsigned short* pb0 = B + (size_t)bn * BN * K + (size_t)srow * K + kb * 8;
    const unsigned short* pb1 = pb0 + (size_t)16 * K;

    // Fragment read bases: contiguous 1KB per (tile, wave) -> conflict-free.
    const unsigned short* fA = As + (4 * (wave >> 1)) * 512 + lane * 8;
    const unsigned short* fB = Bs + (4 * (wave & 1)) * 512 + lane * 8;

    for (int k0 = 0; k0 < K; k0 += BK) {
        gload_lds16(pa0, dstA);
        gload_lds16(pa1, dstA + 512);
        gload_lds16(pb0, dstB);
        gload_lds16(pb1, dstB + 512);
        pa0 += BK; pa1 += BK; pb0 += BK; pb1 += BK;
        __syncthreads();

        bf16x8 af[4], bg[4];
        #pragma unroll
        for (int t = 0; t < 4; ++t) af[t] = *(const bf16x8*)(fA + t * 512);
        #pragma unroll
        for (int t = 0; t < 4; ++t) bg[t] = *(const bf16x8*)(fB + t * 512);

        #pragma unroll
        for (int tm = 0; tm < 4; ++tm)
            #pragma unroll
            for (int tn = 0; tn < 4; ++tn)
                acc[tm][tn] = __builtin_amdgcn_mfma_f32_16x16x32_bf16(
                    af[tm], bg[tn], acc[tm][tn], 0, 0, 0);
        __syncthreads();
    }

    // ---- epilogue: scale, capture diag, exp in place ----
    const int growb = bm * BM + wrow;
    const int gcolb = bn * BN + wcol;

    #pragma unroll
    for (int tm = 0; tm < 4; ++tm)
        #pragma unroll
        for (int tn = 0; tn < 4; ++tn)
            #pragma unroll
            for (int r = 0; r < 4; ++r) {
                const float l = acc[tm][tn][r] * scale;
                const int grow = growb + tm * 16 + quad * 4 + r;
                const int gcol = gcolb + tn * 16 + lanelo;
                if (grow == gcol) diag[grow] = l;
                acc[tm][tn][r] = __expf(l);
            }

    // ---- row sums: reduce over the 16 lanes sharing a row, then atomicAdd ----
    #pragma unroll
    for (int tm = 0; tm < 4; ++tm) {
        floatx4 rs = acc[tm][0] + acc[tm][1] + acc[tm][2] + acc[tm][3];
        #pragma unroll
        for (int r = 0; r < 4; ++r) {
            float v = rs[r];
            v += __shfl_xor(v, 1);
            v += __shfl_xor(v, 2);
            v += __shfl_xor(v, 4);
            v += __shfl_xor(v, 8);
            if (lanelo == 0)
                atomicAdd(&rowsum[growb + tm * 16 + quad * 4 + r], v);
        }
    }

    // ---- col sums: reduce over quads (xor 16, 32), then atomicAdd ----
    #pragma unroll
    for (int tn = 0; tn < 4; ++tn) {
        float cs = 0.f;
        #pragma unroll
        for (int tm = 0; tm < 4; ++tm)
            cs += acc[tm][tn][0] + acc[tm][tn][1] + acc[tm][tn][2] + acc[tm][tn][3];
        cs += __shfl_xor(cs, 16);
        cs += __shfl_xor(cs, 32);
        if (quad == 0)
            atomicAdd(&colsum[gcolb + tn * 16 + lanelo], cs);
    }
}

// ---- Kernel 3: loss = mean( 0.5*(log(rowsum)+log(colsum)) - diag ) ---------
// 32 blocks; out must be pre-zeroed (memsetAsync in kernel_launch).
__global__ __launch_bounds__(256)
void final_reduce(const float* __restrict__ rowsum, const float* __restrict__ colsum,
                  const float* __restrict__ diag, float* __restrict__ out, int n) {
    const int i = blockIdx.x * 256 + threadIdx.x;
    const int t = threadIdx.x;
    float v = 0.5f * (logf(rowsum[i]) + logf(colsum[i])) - diag[i];
    #pragma unroll
    for (int o = 1; o < 64; o <<= 1) v += __shfl_xor(v, o);
    __shared__ float ws[4];
    if ((t & 63) == 0) ws[t >> 6] = v;
    __syncthreads();
    if (t == 0) atomicAdd(out, (ws[0] + ws[1] + ws[2] + ws[3]) / (float)n);
}

extern "C" void kernel_launch(void* const* d_in, const int* in_sizes, int n_in,
                              void* d_out, int out_size, void* d_ws, size_t ws_size,
                              hipStream_t stream) {
    const float* img = (const float*)d_in[0];
    const float* txt = (const float*)d_in[1];
    float* out = (float*)d_out;

    const int D = 1024;
    const int N = in_sizes[0] / D;   // 8192

    unsigned short* imgn = (unsigned short*)d_ws;
    unsigned short* txtn = imgn + (size_t)N * D;
    float* rowsum = (float*)(txtn + (size_t)N * D);
    float* colsum = rowsum + N;
    float* diag = colsum + N;

    normalize_bf16<<<2 * N, 256, 0, stream>>>(img, txt, imgn, txtn, D, N);
    hipMemsetAsync(rowsum, 0, 2 * (size_t)N * sizeof(float), stream);
    hipMemsetAsync(out, 0, sizeof(float), stream);

    dim3 grid(N / BM, N / BN);
    gemm_exp_kernel<<<grid, 256, 0, stream>>>(imgn, txtn, rowsum, colsum, diag,
                                              D, 1.0f / 0.07f);
    final_reduce<<<N / 256, 256, 0, stream>>>(rowsum, colsum, diag, out, N);
}

// Round 4
// 295.444 us; speedup vs baseline: 1.2769x; 1.2769x over previous
//
#include <hip/hip_runtime.h>

// ---------------------------------------------------------------------------
// ContrastiveLoss: loss = mean_i [ 0.5*(LSE_row_i + LSE_col_i) - diag_i ]
// over logits = normalize(img) @ normalize(txt)^T / 0.07, N=8192, D=1024.
// |logit| <= 14.29 -> exp() safe in fp32, no max subtraction needed.
//
// R2 lesson: normalize must cover all D=1024 elems (block-per-row, 256thr x
// float4). R2's wave-per-row only touched 256/row -> absmax 0.31 FAIL.
// GEMM: R0's coalesced global staging + XOR swizzle kb' = kb ^ ((row>>1)&3):
// LDS fragment reads 2-way aliased max (free) instead of 8-way conflicts.
// R1 lesson: global_load_lds lane->address order must stay segment-monotone
// per quarter-wave; permuting rows across lanes cost +27% FETCH, 40% time.
// ---------------------------------------------------------------------------

#define BM 128
#define BN 128
#define BK 32

typedef __bf16 bf16x8 __attribute__((ext_vector_type(8)));
typedef float  floatx4 __attribute__((ext_vector_type(4)));

__device__ __forceinline__ unsigned short f2bf(float f) {
    unsigned int u = __float_as_uint(f);
    u += 0x7fffu + ((u >> 16) & 1u);   // round-to-nearest-even
    return (unsigned short)(u >> 16);
}

__device__ __forceinline__ void gload_lds16(const unsigned short* g, unsigned short* lds) {
    __builtin_amdgcn_global_load_lds(
        (const __attribute__((address_space(1))) void*)g,
        (__attribute__((address_space(3))) void*)lds,
        16, 0, 0);
}

// ---- Kernel 1: row L2-normalize (clamp at eps) + fp32 -> bf16 --------------
// Block per row: 256 threads x float4 = 1024 = D. Blocks [0,N)->img, [N,2N)->txt.
__global__ __launch_bounds__(256)
void normalize_bf16(const float* __restrict__ img, const float* __restrict__ txt,
                    unsigned short* __restrict__ oimg, unsigned short* __restrict__ otxt,
                    int D, int N) {
    const int b = blockIdx.x;
    const float* in = (b < N) ? img : txt;
    unsigned short* out = (b < N) ? oimg : otxt;
    const int row = (b < N) ? b : b - N;
    const int t = threadIdx.x;
    const float4 v = ((const float4*)(in + (size_t)row * D))[t];
    float ss = v.x * v.x + v.y * v.y + v.z * v.z + v.w * v.w;
    #pragma unroll
    for (int o = 1; o < 64; o <<= 1) ss += __shfl_xor(ss, o);
    __shared__ float wss[4];
    if ((t & 63) == 0) wss[t >> 6] = ss;
    __syncthreads();
    const float tot = wss[0] + wss[1] + wss[2] + wss[3];
    const float inv = 1.0f / fmaxf(sqrtf(tot), 1e-8f);
    ushort4 o4;
    o4.x = f2bf(v.x * inv);
    o4.y = f2bf(v.y * inv);
    o4.z = f2bf(v.z * inv);
    o4.w = f2bf(v.w * inv);
    *(ushort4*)(out + (size_t)row * D + t * 4) = o4;
}

// ---- Kernel 2: 128x128-tile NT GEMM + fused exp / row-col sums / diag ------
__global__ __launch_bounds__(256)
void gemm_exp_kernel(const unsigned short* __restrict__ A,   // img_n [N][K] bf16
                     const unsigned short* __restrict__ B,   // txt_n [N][K] bf16
                     float* __restrict__ rowsum, float* __restrict__ colsum,
                     float* __restrict__ diag, int K, float scale) {
    // LDS layout: row-major [128 rows][4 kb-slots of 16B], with kb-slot
    // swizzle: chunk (row, kb) lives at slot kb ^ ((row>>1)&3).
    __shared__ unsigned short As[BM * BK];   // 8 KB
    __shared__ unsigned short Bs[BN * BK];   // 8 KB

    const int bm = blockIdx.x, bn = blockIdx.y;
    const int tid = threadIdx.x;
    const int lane = tid & 63;
    const int wave = tid >> 6;
    const int quad = lane >> 4;
    const int lanelo = lane & 15;
    const int wrow = (wave >> 1) * 64;   // wave quadrant within 128x128
    const int wcol = (wave & 1) * 64;

    floatx4 acc[4][4] = {};

    // Staging (R0 pattern): chunk index c = wave*128 + lane (and +64).
    // LDS pos = c (row = c>>2, slot = c&3); global kb fetched = slot ^ swz(row).
    const int c0 = wave * 128 + lane;
    const int c1 = c0 + 64;
    const int r0 = c0 >> 2, r1 = c1 >> 2;
    const int kg0 = ((c0 & 3) ^ ((r0 >> 1) & 3)) * 8;   // element offset in row
    const int kg1 = ((c1 & 3) ^ ((r1 >> 1) & 3)) * 8;

    const unsigned short* pa0 = A + (size_t)bm * BM * K + (size_t)r0 * K + kg0;
    const unsigned short* pa1 = A + (size_t)bm * BM * K + (size_t)r1 * K + kg1;
    const unsigned short* pb0 = B + (size_t)bn * BN * K + (size_t)r0 * K + kg0;
    const unsigned short* pb1 = B + (size_t)bn * BN * K + (size_t)r1 * K + kg1;
    unsigned short* dA0 = As + c0 * 8;
    unsigned short* dA1 = As + c1 * 8;
    unsigned short* dB0 = Bs + c0 * 8;
    unsigned short* dB1 = Bs + c1 * 8;

    for (int k0 = 0; k0 < K; k0 += BK) {
        gload_lds16(pa0, dA0);
        gload_lds16(pa1, dA1);
        gload_lds16(pb0, dB0);
        gload_lds16(pb1, dB1);
        pa0 += BK; pa1 += BK; pb0 += BK; pb1 += BK;
        __syncthreads();

        bf16x8 af[4], bg[4];
        #pragma unroll
        for (int t = 0; t < 4; ++t) {
            const int R = wrow + t * 16 + lanelo;
            af[t] = *(const bf16x8*)(As + R * 32 + (quad ^ ((R >> 1) & 3)) * 8);
        }
        #pragma unroll
        for (int t = 0; t < 4; ++t) {
            const int R = wcol + t * 16 + lanelo;
            bg[t] = *(const bf16x8*)(Bs + R * 32 + (quad ^ ((R >> 1) & 3)) * 8);
        }

        #pragma unroll
        for (int tm = 0; tm < 4; ++tm)
            #pragma unroll
            for (int tn = 0; tn < 4; ++tn)
                acc[tm][tn] = __builtin_amdgcn_mfma_f32_16x16x32_bf16(
                    af[tm], bg[tn], acc[tm][tn], 0, 0, 0);
        __syncthreads();
    }

    // ---- epilogue: scale, capture diag, exp in place ----
    const int growb = bm * BM + wrow;
    const int gcolb = bn * BN + wcol;

    #pragma unroll
    for (int tm = 0; tm < 4; ++tm)
        #pragma unroll
        for (int tn = 0; tn < 4; ++tn)
            #pragma unroll
            for (int r = 0; r < 4; ++r) {
                const float l = acc[tm][tn][r] * scale;
                const int grow = growb + tm * 16 + quad * 4 + r;
                const int gcol = gcolb + tn * 16 + lanelo;
                if (grow == gcol) diag[grow] = l;
                acc[tm][tn][r] = __expf(l);
            }

    // ---- row sums: reduce over the 16 lanes sharing a row, then atomicAdd ----
    #pragma unroll
    for (int tm = 0; tm < 4; ++tm) {
        floatx4 rs = acc[tm][0] + acc[tm][1] + acc[tm][2] + acc[tm][3];
        #pragma unroll
        for (int r = 0; r < 4; ++r) {
            float v = rs[r];
            v += __shfl_xor(v, 1);
            v += __shfl_xor(v, 2);
            v += __shfl_xor(v, 4);
            v += __shfl_xor(v, 8);
            if (lanelo == 0)
                atomicAdd(&rowsum[growb + tm * 16 + quad * 4 + r], v);
        }
    }

    // ---- col sums: reduce over quads (xor 16, 32), then atomicAdd ----
    #pragma unroll
    for (int tn = 0; tn < 4; ++tn) {
        float cs = 0.f;
        #pragma unroll
        for (int tm = 0; tm < 4; ++tm)
            cs += acc[tm][tn][0] + acc[tm][tn][1] + acc[tm][tn][2] + acc[tm][tn][3];
        cs += __shfl_xor(cs, 16);
        cs += __shfl_xor(cs, 32);
        if (quad == 0)
            atomicAdd(&colsum[gcolb + tn * 16 + lanelo], cs);
    }
}

// ---- Kernel 3: loss = mean( 0.5*(log(rowsum)+log(colsum)) - diag ) ---------
// out must be pre-zeroed (memsetAsync in kernel_launch).
__global__ __launch_bounds__(256)
void final_reduce(const float* __restrict__ rowsum, const float* __restrict__ colsum,
                  const float* __restrict__ diag, float* __restrict__ out, int n) {
    const int i = blockIdx.x * 256 + threadIdx.x;
    const int t = threadIdx.x;
    float v = 0.5f * (logf(rowsum[i]) + logf(colsum[i])) - diag[i];
    #pragma unroll
    for (int o = 1; o < 64; o <<= 1) v += __shfl_xor(v, o);
    __shared__ float ws[4];
    if ((t & 63) == 0) ws[t >> 6] = v;
    __syncthreads();
    if (t == 0) atomicAdd(out, (ws[0] + ws[1] + ws[2] + ws[3]) / (float)n);
}

extern "C" void kernel_launch(void* const* d_in, const int* in_sizes, int n_in,
                              void* d_out, int out_size, void* d_ws, size_t ws_size,
                              hipStream_t stream) {
    const float* img = (const float*)d_in[0];
    const float* txt = (const float*)d_in[1];
    float* out = (float*)d_out;

    const int D = 1024;
    const int N = in_sizes[0] / D;   // 8192

    unsigned short* imgn = (unsigned short*)d_ws;
    unsigned short* txtn = imgn + (size_t)N * D;
    float* rowsum = (float*)(txtn + (size_t)N * D);
    float* colsum = rowsum + N;
    float* diag = colsum + N;

    normalize_bf16<<<2 * N, 256, 0, stream>>>(img, txt, imgn, txtn, D, N);
    hipMemsetAsync(rowsum, 0, 2 * (size_t)N * sizeof(float), stream);
    hipMemsetAsync(out, 0, sizeof(float), stream);

    dim3 grid(N / BM, N / BN);
    gemm_exp_kernel<<<grid, 256, 0, stream>>>(imgn, txtn, rowsum, colsum, diag,
                                              D, 1.0f / 0.07f);
    final_reduce<<<N / 256, 256, 0, stream>>>(rowsum, colsum, diag, out, N);
}

// Round 5
// 230.724 us; speedup vs baseline: 1.6350x; 1.2805x over previous
//
#include <hip/hip_runtime.h>

// ---------------------------------------------------------------------------
// ContrastiveLoss: loss = mean_i [ 0.5*(LSE_row_i + LSE_col_i) - diag_i ]
// over logits = normalize(img) @ normalize(txt)^T / 0.07, N=8192, D=1024.
// |logit| <= 14.29 -> exp() safe in fp32, no max subtraction needed.
//
// R4: fp8 e4m3 GEMM (m145 ladder step). Inputs quantized at x16 scale into
// OCP e4m3 (range +-2.5 << 448). MFMA 16x16x32_fp8_fp8 = bf16 rate, but LDS
// fragment bytes and staging bytes halve -> LDS pipe no longer the pacer.
// BK=64 bytes keeps LDS geometry byte-identical to the proven R3 layout:
// 64B rows, 4x16B chunks, XOR swizzle slot = chunk ^ ((row>>1)&3) (2-way
// max aliasing = free), 64B-per-row global segments (R1 lesson: keep
// quarter-wave lane->address segment-monotone). Barrier count halves (16).
// C/D layout is dtype-independent -> epilogue identical to R3 (absmax 0.0),
// with scale 1/(256*0.07) to undo the x16 quantization on both sides.
// ---------------------------------------------------------------------------

#define BM 128
#define BN 128
#define BKB 64   // fp8 elements (bytes) of K per iteration

typedef float floatx4 __attribute__((ext_vector_type(4)));

__device__ __forceinline__ void gload_lds16(const unsigned char* g, unsigned char* lds) {
    __builtin_amdgcn_global_load_lds(
        (const __attribute__((address_space(1))) void*)g,
        (__attribute__((address_space(3))) void*)lds,
        16, 0, 0);
}

// ---- Kernel 1: row L2-normalize (clamp at eps), x16, fp32 -> fp8 e4m3 ------
// Block per row: 256 threads x float4 = 1024 = D. Blocks [0,N)->img, [N,2N)->txt.
__global__ __launch_bounds__(256)
void normalize_fp8(const float* __restrict__ img, const float* __restrict__ txt,
                   unsigned int* __restrict__ oimg, unsigned int* __restrict__ otxt,
                   int D, int N) {
    const int b = blockIdx.x;
    const float* in = (b < N) ? img : txt;
    unsigned int* out = (b < N) ? oimg : otxt;
    const int row = (b < N) ? b : b - N;
    const int t = threadIdx.x;
    const float4 v = ((const float4*)(in + (size_t)row * D))[t];
    float ss = v.x * v.x + v.y * v.y + v.z * v.z + v.w * v.w;
    #pragma unroll
    for (int o = 1; o < 64; o <<= 1) ss += __shfl_xor(ss, o);
    __shared__ float wss[4];
    if ((t & 63) == 0) wss[t >> 6] = ss;
    __syncthreads();
    const float tot = wss[0] + wss[1] + wss[2] + wss[3];
    const float inv = 16.0f / fmaxf(sqrtf(tot), 1e-8f);   // x16 quantization scale
    int p = __builtin_amdgcn_cvt_pk_fp8_f32(v.x * inv, v.y * inv, 0, false);
    p = __builtin_amdgcn_cvt_pk_fp8_f32(v.z * inv, v.w * inv, p, true);
    out[(size_t)row * (D / 4) + t] = (unsigned int)p;
}

// ---- Kernel 2: 128x128-tile NT fp8 GEMM + fused exp / row-col sums / diag --
__global__ __launch_bounds__(256)
void gemm_exp_kernel(const unsigned char* __restrict__ A,   // img_q [N][K] fp8
                     const unsigned char* __restrict__ B,   // txt_q [N][K] fp8
                     float* __restrict__ rowsum, float* __restrict__ colsum,
                     float* __restrict__ diag, int K, float scale) {
    // LDS: [128 rows][64 bytes], 4 x 16B chunks per row, chunk slot swizzled
    // by ((row>>1)&3). Identical byte geometry to the verified R3 layout.
    __shared__ unsigned char As[BM * BKB];   // 8 KB
    __shared__ unsigned char Bs[BN * BKB];   // 8 KB

    const int bm = blockIdx.x, bn = blockIdx.y;
    const int tid = threadIdx.x;
    const int lane = tid & 63;
    const int wave = tid >> 6;
    const int quad = lane >> 4;
    const int lanelo = lane & 15;
    const int wrow = (wave >> 1) * 64;   // wave quadrant within 128x128
    const int wcol = (wave & 1) * 64;

    floatx4 acc[4][4] = {};

    // Staging: 512 16B chunks per tile; c = wave*128 + lane (and +64).
    // LDS slot = c&3; global chunk fetched = slot ^ swz(row).
    const int c0 = wave * 128 + lane;
    const int c1 = c0 + 64;
    const int r0 = c0 >> 2, r1 = c1 >> 2;
    const int kg0 = ((c0 & 3) ^ ((r0 >> 1) & 3)) * 16;   // byte offset in window
    const int kg1 = ((c1 & 3) ^ ((r1 >> 1) & 3)) * 16;

    const unsigned char* pa0 = A + (size_t)bm * BM * K + (size_t)r0 * K + kg0;
    const unsigned char* pa1 = A + (size_t)bm * BM * K + (size_t)r1 * K + kg1;
    const unsigned char* pb0 = B + (size_t)bn * BN * K + (size_t)r0 * K + kg0;
    const unsigned char* pb1 = B + (size_t)bn * BN * K + (size_t)r1 * K + kg1;
    unsigned char* dA0 = As + c0 * 16;
    unsigned char* dA1 = As + c1 * 16;
    unsigned char* dB0 = Bs + c0 * 16;
    unsigned char* dB1 = Bs + c1 * 16;

    // Fragment LDS byte offsets (loop-invariant). For k-half h (32 elems of
    // MFMA k) lane needs global bytes h*32 + quad*8 + [0,8) of its row:
    // chunk g = h*2 + (quad>>1), LDS slot = g ^ swz(R), byte = (quad&1)*8.
    int aoff[2][4], boff[2][4];
    #pragma unroll
    for (int h = 0; h < 2; ++h)
        #pragma unroll
        for (int t = 0; t < 4; ++t) {
            const int Ra = wrow + t * 16 + lanelo;
            const int Rb = wcol + t * 16 + lanelo;
            const int g = h * 2 + (quad >> 1);
            const int byt = (quad & 1) * 8;
            aoff[h][t] = Ra * 64 + ((g ^ ((Ra >> 1) & 3)) * 16) + byt;
            boff[h][t] = Rb * 64 + ((g ^ ((Rb >> 1) & 3)) * 16) + byt;
        }

    for (int k0 = 0; k0 < K; k0 += BKB) {
        gload_lds16(pa0, dA0);
        gload_lds16(pa1, dA1);
        gload_lds16(pb0, dB0);
        gload_lds16(pb1, dB1);
        pa0 += BKB; pa1 += BKB; pb0 += BKB; pb1 += BKB;
        __syncthreads();

        long af[2][4], bg[2][4];
        #pragma unroll
        for (int h = 0; h < 2; ++h)
            #pragma unroll
            for (int t = 0; t < 4; ++t) {
                af[h][t] = *(const long*)(As + aoff[h][t]);
                bg[h][t] = *(const long*)(Bs + boff[h][t]);
            }

        #pragma unroll
        for (int h = 0; h < 2; ++h)
            #pragma unroll
            for (int tm = 0; tm < 4; ++tm)
                #pragma unroll
                for (int tn = 0; tn < 4; ++tn)
                    acc[tm][tn] = __builtin_amdgcn_mfma_f32_16x16x32_fp8_fp8(
                        af[h][tm], bg[h][tn], acc[tm][tn], 0, 0, 0);
        __syncthreads();
    }

    // ---- epilogue: scale, capture diag, exp in place ----
    const int growb = bm * BM + wrow;
    const int gcolb = bn * BN + wcol;

    #pragma unroll
    for (int tm = 0; tm < 4; ++tm)
        #pragma unroll
        for (int tn = 0; tn < 4; ++tn)
            #pragma unroll
            for (int r = 0; r < 4; ++r) {
                const float l = acc[tm][tn][r] * scale;
                const int grow = growb + tm * 16 + quad * 4 + r;
                const int gcol = gcolb + tn * 16 + lanelo;
                if (grow == gcol) diag[grow] = l;
                acc[tm][tn][r] = __expf(l);
            }

    // ---- row sums: reduce over the 16 lanes sharing a row, then atomicAdd ----
    #pragma unroll
    for (int tm = 0; tm < 4; ++tm) {
        floatx4 rs = acc[tm][0] + acc[tm][1] + acc[tm][2] + acc[tm][3];
        #pragma unroll
        for (int r = 0; r < 4; ++r) {
            float v = rs[r];
            v += __shfl_xor(v, 1);
            v += __shfl_xor(v, 2);
            v += __shfl_xor(v, 4);
            v += __shfl_xor(v, 8);
            if (lanelo == 0)
                atomicAdd(&rowsum[growb + tm * 16 + quad * 4 + r], v);
        }
    }

    // ---- col sums: reduce over quads (xor 16, 32), then atomicAdd ----
    #pragma unroll
    for (int tn = 0; tn < 4; ++tn) {
        float cs = 0.f;
        #pragma unroll
        for (int tm = 0; tm < 4; ++tm)
            cs += acc[tm][tn][0] + acc[tm][tn][1] + acc[tm][tn][2] + acc[tm][tn][3];
        cs += __shfl_xor(cs, 16);
        cs += __shfl_xor(cs, 32);
        if (quad == 0)
            atomicAdd(&colsum[gcolb + tn * 16 + lanelo], cs);
    }
}

// ---- Kernel 3: loss = mean( 0.5*(log(rowsum)+log(colsum)) - diag ) ---------
// out must be pre-zeroed (memsetAsync in kernel_launch).
__global__ __launch_bounds__(256)
void final_reduce(const float* __restrict__ rowsum, const float* __restrict__ colsum,
                  const float* __restrict__ diag, float* __restrict__ out, int n) {
    const int i = blockIdx.x * 256 + threadIdx.x;
    const int t = threadIdx.x;
    float v = 0.5f * (logf(rowsum[i]) + logf(colsum[i])) - diag[i];
    #pragma unroll
    for (int o = 1; o < 64; o <<= 1) v += __shfl_xor(v, o);
    __shared__ float ws[4];
    if ((t & 63) == 0) ws[t >> 6] = v;
    __syncthreads();
    if (t == 0) atomicAdd(out, (ws[0] + ws[1] + ws[2] + ws[3]) / (float)n);
}

extern "C" void kernel_launch(void* const* d_in, const int* in_sizes, int n_in,
                              void* d_out, int out_size, void* d_ws, size_t ws_size,
                              hipStream_t stream) {
    const float* img = (const float*)d_in[0];
    const float* txt = (const float*)d_in[1];
    float* out = (float*)d_out;

    const int D = 1024;
    const int N = in_sizes[0] / D;   // 8192

    unsigned char* imgq = (unsigned char*)d_ws;
    unsigned char* txtq = imgq + (size_t)N * D;
    float* rowsum = (float*)(txtq + (size_t)N * D);
    float* colsum = rowsum + N;
    float* diag = colsum + N;

    normalize_fp8<<<2 * N, 256, 0, stream>>>(img, txt, (unsigned int*)imgq,
                                             (unsigned int*)txtq, D, N);
    hipMemsetAsync(rowsum, 0, 2 * (size_t)N * sizeof(float), stream);
    hipMemsetAsync(out, 0, sizeof(float), stream);

    dim3 grid(N / BM, N / BN);
    // acc = sum of (16a)(16b) = 256*cos; scale undoes 256 and applies 1/T.
    gemm_exp_kernel<<<grid, 256, 0, stream>>>(imgq, txtq, rowsum, colsum, diag,
                                              D, 1.0f / (256.0f * 0.07f));
    final_reduce<<<N / 256, 256, 0, stream>>>(rowsum, colsum, diag, out, N);
}

// Round 6
// 215.079 us; speedup vs baseline: 1.7540x; 1.0727x over previous
//
#include <hip/hip_runtime.h>

// ---------------------------------------------------------------------------
// ContrastiveLoss: loss = mean_i [ 0.5*(LSE_row_i + LSE_col_i) - diag_i ]
// over logits = normalize(img) @ normalize(txt)^T / 0.07, N=8192, D=1024.
// |logit| <= 14.29 -> exp() safe in fp32, no max subtraction needed.
//
// R5: fp8 e4m3 GEMM with PRE-INTERLEAVED rows. normalize_fp8 stores each
// 64-elem k-window with 8B units ordered [u0,u4,u1,u5,u2,u6,u3,u7], so LDS
// 16B chunk q holds lane-quad q's fragments for BOTH 32-k MFMA halves
// (h0 = low 8B, h1 = high 8B). Fragment read = one ds_read_b128 per tile,
// byte-identical to R3's measured-conflict-free pattern.
// R4 lesson: ds_read_b64 under a 16B-granular swizzle still 2-way-conflicts
// within a dword phase (1.678e7 conflicts) - b128 is the conflict-free width.
// R1 lesson: staging lane->address must stay segment-monotone per
// quarter-wave (64B row segments, XOR slot swizzle ((row>>1)&3)).
// Zero-init of rowsum/colsum/out folded into normalize (stream-ordered).
// ---------------------------------------------------------------------------

#define BM 128
#define BN 128
#define BKB 64   // fp8 elements (bytes) of K per iteration

typedef float floatx4 __attribute__((ext_vector_type(4)));
typedef long  longx2  __attribute__((ext_vector_type(2)));

__device__ __forceinline__ void gload_lds16(const unsigned char* g, unsigned char* lds) {
    __builtin_amdgcn_global_load_lds(
        (const __attribute__((address_space(1))) void*)g,
        (__attribute__((address_space(3))) void*)lds,
        16, 0, 0);
}

// ---- Kernel 1: row L2-normalize, x16, fp32 -> fp8 e4m3, interleaved store --
// Block per row: 256 threads x float4 = 1024 = D. Blocks [0,N)->img, [N,2N)->txt.
// Within each 64-elem window, 8B unit u goes to position p = 2*(u&3) + (u>>2).
// Side duty: blocks 0..63 zero rowsum/colsum (2N contiguous floats); block 0
// thread 0 zeros out. Safe: normalize finishes before GEMM/final_reduce start.
__global__ __launch_bounds__(256)
void normalize_fp8(const float* __restrict__ img, const float* __restrict__ txt,
                   unsigned int* __restrict__ oimg, unsigned int* __restrict__ otxt,
                   float* __restrict__ sums, float* __restrict__ out, int D, int N) {
    const int b = blockIdx.x;
    const int t = threadIdx.x;
    if (b < (2 * N + 255) / 256) {
        const int i = b * 256 + t;
        if (i < 2 * N) sums[i] = 0.f;
        if (b == 0 && t == 0) out[0] = 0.f;
    }
    const float* in = (b < N) ? img : txt;
    unsigned int* o = (b < N) ? oimg : otxt;
    const int row = (b < N) ? b : b - N;
    const float4 v = ((const float4*)(in + (size_t)row * D))[t];
    float ss = v.x * v.x + v.y * v.y + v.z * v.z + v.w * v.w;
    #pragma unroll
    for (int o2 = 1; o2 < 64; o2 <<= 1) ss += __shfl_xor(ss, o2);
    __shared__ float wss[4];
    if ((t & 63) == 0) wss[t >> 6] = ss;
    __syncthreads();
    const float tot = wss[0] + wss[1] + wss[2] + wss[3];
    const float inv = 16.0f / fmaxf(sqrtf(tot), 1e-8f);   // x16 quantization scale
    int p = __builtin_amdgcn_cvt_pk_fp8_f32(v.x * inv, v.y * inv, 0, false);
    p = __builtin_amdgcn_cvt_pk_fp8_f32(v.z * inv, v.w * inv, p, true);
    // interleaved dword index within row: window w = t>>4, tw = t&15,
    // unit u = tw>>1, pos = 2*(u&3) + (u>>2), dword = w*16 + pos*2 + (tw&1)
    const int w = t >> 4, tw = t & 15, u = tw >> 1;
    const int pos = 2 * (u & 3) + (u >> 2);
    o[(size_t)row * (D / 4) + w * 16 + pos * 2 + (tw & 1)] = (unsigned int)p;
}

// ---- Kernel 2: 128x128-tile NT fp8 GEMM + fused exp / row-col sums / diag --
__global__ __launch_bounds__(256)
void gemm_exp_kernel(const unsigned char* __restrict__ A,   // img_q [N][K] fp8 (interleaved windows)
                     const unsigned char* __restrict__ B,   // txt_q [N][K] fp8
                     float* __restrict__ rowsum, float* __restrict__ colsum,
                     float* __restrict__ diag, int K, float scale) {
    // LDS: [128 rows][64 bytes], 4 x 16B chunks per row, chunk slot swizzled
    // by ((row>>1)&3). Byte geometry identical to the verified R3 layout.
    __shared__ unsigned char As[BM * BKB];   // 8 KB
    __shared__ unsigned char Bs[BN * BKB];   // 8 KB

    const int bm = blockIdx.x, bn = blockIdx.y;
    const int tid = threadIdx.x;
    const int lane = tid & 63;
    const int wave = tid >> 6;
    const int quad = lane >> 4;
    const int lanelo = lane & 15;
    const int wrow = (wave >> 1) * 64;   // wave quadrant within 128x128
    const int wcol = (wave & 1) * 64;

    floatx4 acc[4][4] = {};

    // Staging: 512 16B chunks per tile; c = wave*128 + lane (and +64).
    // LDS slot = c&3; global chunk fetched = slot ^ swz(row).
    const int c0 = wave * 128 + lane;
    const int c1 = c0 + 64;
    const int r0 = c0 >> 2, r1 = c1 >> 2;
    const int kg0 = ((c0 & 3) ^ ((r0 >> 1) & 3)) * 16;   // byte offset in window
    const int kg1 = ((c1 & 3) ^ ((r1 >> 1) & 3)) * 16;

    const unsigned char* pa0 = A + (size_t)bm * BM * K + (size_t)r0 * K + kg0;
    const unsigned char* pa1 = A + (size_t)bm * BM * K + (size_t)r1 * K + kg1;
    const unsigned char* pb0 = B + (size_t)bn * BN * K + (size_t)r0 * K + kg0;
    const unsigned char* pb1 = B + (size_t)bn * BN * K + (size_t)r1 * K + kg1;
    unsigned char* dA0 = As + c0 * 16;
    unsigned char* dA1 = As + c1 * 16;
    unsigned char* dB0 = Bs + c0 * 16;
    unsigned char* dB1 = Bs + c1 * 16;

    // Fragment LDS byte offsets (loop-invariant): chunk quad^swz(R) of row R.
    // b128 = [h0 fragment (8B) | h1 fragment (8B)] thanks to the interleave.
    int aoff[4], boff[4];
    #pragma unroll
    for (int t = 0; t < 4; ++t) {
        const int Ra = wrow + t * 16 + lanelo;
        const int Rb = wcol + t * 16 + lanelo;
        aoff[t] = Ra * 64 + ((quad ^ ((Ra >> 1) & 3)) * 16);
        boff[t] = Rb * 64 + ((quad ^ ((Rb >> 1) & 3)) * 16);
    }

    for (int k0 = 0; k0 < K; k0 += BKB) {
        gload_lds16(pa0, dA0);
        gload_lds16(pa1, dA1);
        gload_lds16(pb0, dB0);
        gload_lds16(pb1, dB1);
        pa0 += BKB; pa1 += BKB; pb0 += BKB; pb1 += BKB;
        __syncthreads();

        longx2 af[4], bg[4];
        #pragma unroll
        for (int t = 0; t < 4; ++t) {
            af[t] = *(const longx2*)(As + aoff[t]);
            bg[t] = *(const longx2*)(Bs + boff[t]);
        }

        #pragma unroll
        for (int tm = 0; tm < 4; ++tm)
            #pragma unroll
            for (int tn = 0; tn < 4; ++tn) {
                acc[tm][tn] = __builtin_amdgcn_mfma_f32_16x16x32_fp8_fp8(
                    af[tm].x, bg[tn].x, acc[tm][tn], 0, 0, 0);
                acc[tm][tn] = __builtin_amdgcn_mfma_f32_16x16x32_fp8_fp8(
                    af[tm].y, bg[tn].y, acc[tm][tn], 0, 0, 0);
            }
        __syncthreads();
    }

    // ---- epilogue: scale, capture diag, exp in place ----
    const int growb = bm * BM + wrow;
    const int gcolb = bn * BN + wcol;

    #pragma unroll
    for (int tm = 0; tm < 4; ++tm)
        #pragma unroll
        for (int tn = 0; tn < 4; ++tn)
            #pragma unroll
            for (int r = 0; r < 4; ++r) {
                const float l = acc[tm][tn][r] * scale;
                const int grow = growb + tm * 16 + quad * 4 + r;
                const int gcol = gcolb + tn * 16 + lanelo;
                if (grow == gcol) diag[grow] = l;
                acc[tm][tn][r] = __expf(l);
            }

    // ---- row sums: reduce over the 16 lanes sharing a row, then atomicAdd ----
    #pragma unroll
    for (int tm = 0; tm < 4; ++tm) {
        floatx4 rs = acc[tm][0] + acc[tm][1] + acc[tm][2] + acc[tm][3];
        #pragma unroll
        for (int r = 0; r < 4; ++r) {
            float v = rs[r];
            v += __shfl_xor(v, 1);
            v += __shfl_xor(v, 2);
            v += __shfl_xor(v, 4);
            v += __shfl_xor(v, 8);
            if (lanelo == 0)
                atomicAdd(&rowsum[growb + tm * 16 + quad * 4 + r], v);
        }
    }

    // ---- col sums: reduce over quads (xor 16, 32), then atomicAdd ----
    #pragma unroll
    for (int tn = 0; tn < 4; ++tn) {
        float cs = 0.f;
        #pragma unroll
        for (int tm = 0; tm < 4; ++tm)
            cs += acc[tm][tn][0] + acc[tm][tn][1] + acc[tm][tn][2] + acc[tm][tn][3];
        cs += __shfl_xor(cs, 16);
        cs += __shfl_xor(cs, 32);
        if (quad == 0)
            atomicAdd(&colsum[gcolb + tn * 16 + lanelo], cs);
    }
}

// ---- Kernel 3: loss = mean( 0.5*(log(rowsum)+log(colsum)) - diag ) ---------
// out zeroed by normalize_fp8 (stream-ordered before this kernel).
__global__ __launch_bounds__(256)
void final_reduce(const float* __restrict__ rowsum, const float* __restrict__ colsum,
                  const float* __restrict__ diag, float* __restrict__ out, int n) {
    const int i = blockIdx.x * 256 + threadIdx.x;
    const int t = threadIdx.x;
    float v = 0.5f * (logf(rowsum[i]) + logf(colsum[i])) - diag[i];
    #pragma unroll
    for (int o = 1; o < 64; o <<= 1) v += __shfl_xor(v, o);
    __shared__ float ws[4];
    if ((t & 63) == 0) ws[t >> 6] = v;
    __syncthreads();
    if (t == 0) atomicAdd(out, (ws[0] + ws[1] + ws[2] + ws[3]) / (float)n);
}

extern "C" void kernel_launch(void* const* d_in, const int* in_sizes, int n_in,
                              void* d_out, int out_size, void* d_ws, size_t ws_size,
                              hipStream_t stream) {
    const float* img = (const float*)d_in[0];
    const float* txt = (const float*)d_in[1];
    float* out = (float*)d_out;

    const int D = 1024;
    const int N = in_sizes[0] / D;   // 8192

    unsigned char* imgq = (unsigned char*)d_ws;
    unsigned char* txtq = imgq + (size_t)N * D;
    float* rowsum = (float*)(txtq + (size_t)N * D);   // rowsum[N] ++ colsum[N]
    float* colsum = rowsum + N;
    float* diag = colsum + N;

    normalize_fp8<<<2 * N, 256, 0, stream>>>(img, txt, (unsigned int*)imgq,
                                             (unsigned int*)txtq, rowsum, out, D, N);

    dim3 grid(N / BM, N / BN);
    // acc = sum of (16a)(16b) = 256*cos; scale undoes 256 and applies 1/T.
    gemm_exp_kernel<<<grid, 256, 0, stream>>>(imgq, txtq, rowsum, colsum, diag,
                                              D, 1.0f / (256.0f * 0.07f));
    final_reduce<<<N / 256, 256, 0, stream>>>(rowsum, colsum, diag, out, N);
}

// Round 7
// 191.115 us; speedup vs baseline: 1.9739x; 1.1254x over previous
//
#include <hip/hip_runtime.h>

// ---------------------------------------------------------------------------
// ContrastiveLoss: loss = mean_i [ 0.5*(LSE_row_i + LSE_col_i) - diag_i ]
// over logits = normalize(img) @ normalize(txt)^T / 0.07, N=8192, D=1024.
// |logit| <= 14.29 -> exp() safe in fp32, no max subtraction needed.
//
// R6: MX-scaled fp8 K=128 (mfma_scale_f32_16x16x128_f8f6f4, scales=1.0) =
// 2x fp8 MFMA rate (m148: 1628 TF vs m145 995 TF on this structure).
// BK=128 staged as TWO 64B windows, each with the R5-proven geometry:
// 64B rows, 4x16B slots, XOR swizzle slot = chunk ^ ((row>>1)&3).
// Lane fragment (32 contiguous k-bytes, k = quad*32+[0,32)) = chunks
// (quad&1)*2, +1 of window quad>>1 -> two ds_read_b128 at addr, addr^16;
// same quarter-wave bank multiset as R5 -> zero conflicts (measured R5/R3).
// R4 lesson: b64 reads conflict under 16B swizzle - b128 only.
// R1 lesson: staging lane->addr stays segment-monotone per quarter-wave.
// Normalize: wave-per-row, no barrier; zero-init of sums/out folded in.
// ---------------------------------------------------------------------------

#define BM 128
#define BN 128
#define BKB 128   // fp8 K-bytes per iteration (one MFMA k-step)

typedef float floatx4 __attribute__((ext_vector_type(4)));
typedef int   intx8   __attribute__((ext_vector_type(8)));

__device__ __forceinline__ void gload_lds16(const unsigned char* g, unsigned char* lds) {
    __builtin_amdgcn_global_load_lds(
        (const __attribute__((address_space(1))) void*)g,
        (__attribute__((address_space(3))) void*)lds,
        16, 0, 0);
}

// ---- Kernel 1: row L2-normalize, x16, fp32 -> fp8 e4m3 (contiguous k) ------
// One wave per row (16 floats/lane), 4 rows per block. Rows [0,N)->img,
// [N,2N)->txt. Side duty: zero rowsum/colsum (2N floats) and out.
__global__ __launch_bounds__(256)
void normalize_fp8(const float* __restrict__ img, const float* __restrict__ txt,
                   unsigned int* __restrict__ oimg, unsigned int* __restrict__ otxt,
                   float* __restrict__ sums, float* __restrict__ out, int N) {
    const int gi = blockIdx.x * 256 + threadIdx.x;
    if (gi < 2 * N) sums[gi] = 0.f;
    if (gi == 0) out[0] = 0.f;

    const int gw = blockIdx.x * 4 + (threadIdx.x >> 6);   // row id in [0,2N)
    const int lane = threadIdx.x & 63;
    const float* in = (gw < N) ? img : txt;
    unsigned int* o = (gw < N) ? oimg : otxt;
    const int row = (gw < N) ? gw : gw - N;
    const float4* rp = (const float4*)(in + (size_t)row * 1024);

    float4 v[4];
    float ss = 0.f;
    #pragma unroll
    for (int j = 0; j < 4; ++j) {
        v[j] = rp[j * 64 + lane];
        ss += v[j].x * v[j].x + v[j].y * v[j].y + v[j].z * v[j].z + v[j].w * v[j].w;
    }
    #pragma unroll
    for (int o2 = 1; o2 < 64; o2 <<= 1) ss += __shfl_xor(ss, o2);
    const float inv = 16.0f / fmaxf(sqrtf(ss), 1e-8f);   // x16 quantization scale
    #pragma unroll
    for (int j = 0; j < 4; ++j) {
        int p = __builtin_amdgcn_cvt_pk_fp8_f32(v[j].x * inv, v[j].y * inv, 0, false);
        p = __builtin_amdgcn_cvt_pk_fp8_f32(v[j].z * inv, v[j].w * inv, p, true);
        o[(size_t)row * 256 + j * 64 + lane] = (unsigned int)p;
    }
}

// ---- Kernel 2: 128x128-tile NT MX-fp8 GEMM + fused exp/row-col sums/diag ---
__global__ __launch_bounds__(256)
void gemm_exp_kernel(const unsigned char* __restrict__ A,   // img_q [N][K] fp8
                     const unsigned char* __restrict__ B,   // txt_q [N][K] fp8
                     float* __restrict__ rowsum, float* __restrict__ colsum,
                     float* __restrict__ diag, int K, float scale) {
    // LDS: per matrix, 2 windows x [128 rows][64B], slot = chunk ^ ((R>>1)&3).
    __shared__ unsigned char As[2 * BM * 64];   // 16 KB
    __shared__ unsigned char Bs[2 * BN * 64];   // 16 KB

    const int bm = blockIdx.x, bn = blockIdx.y;
    const int tid = threadIdx.x;
    const int lane = tid & 63;
    const int wave = tid >> 6;
    const int quad = lane >> 4;
    const int lanelo = lane & 15;
    const int wrow = (wave >> 1) * 64;   // wave quadrant within 128x128
    const int wcol = (wave & 1) * 64;

    floatx4 acc[4][4] = {};

    // Staging (per window): chunk c = wave*128 + lane (and +64); LDS slot =
    // c&3 of row c>>2; global chunk fetched = slot ^ swz(row).
    const int c0 = wave * 128 + lane;
    const int c1 = c0 + 64;
    const int r0 = c0 >> 2, r1 = c1 >> 2;
    const int kg0 = ((c0 & 3) ^ ((r0 >> 1) & 3)) * 16;   // byte in 64B window
    const int kg1 = ((c1 & 3) ^ ((r1 >> 1) & 3)) * 16;

    const unsigned char* pa0 = A + (size_t)bm * BM * K + (size_t)r0 * K + kg0;
    const unsigned char* pa1 = A + (size_t)bm * BM * K + (size_t)r1 * K + kg1;
    const unsigned char* pb0 = B + (size_t)bn * BN * K + (size_t)r0 * K + kg0;
    const unsigned char* pb1 = B + (size_t)bn * BN * K + (size_t)r1 * K + kg1;
    unsigned char* dA0 = As + c0 * 16;
    unsigned char* dA1 = As + c1 * 16;
    unsigned char* dB0 = Bs + c0 * 16;
    unsigned char* dB1 = Bs + c1 * 16;

    // Fragment LDS offsets (loop-invariant): window = quad>>1, first chunk
    // cA = (quad&1)*2, slot = cA ^ swz(R); second chunk at addr ^ 16.
    int aoff[4], boff[4];
    #pragma unroll
    for (int t = 0; t < 4; ++t) {
        const int Ra = wrow + t * 16 + lanelo;
        const int Rb = wcol + t * 16 + lanelo;
        const int cA = (quad & 1) * 2;
        aoff[t] = (quad >> 1) * 8192 + Ra * 64 + ((cA ^ ((Ra >> 1) & 3)) * 16);
        boff[t] = (quad >> 1) * 8192 + Rb * 64 + ((cA ^ ((Rb >> 1) & 3)) * 16);
    }

    for (int k0 = 0; k0 < K; k0 += BKB) {
        #pragma unroll
        for (int w = 0; w < 2; ++w) {
            gload_lds16(pa0 + w * 64, dA0 + w * 8192);
            gload_lds16(pa1 + w * 64, dA1 + w * 8192);
            gload_lds16(pb0 + w * 64, dB0 + w * 8192);
            gload_lds16(pb1 + w * 64, dB1 + w * 8192);
        }
        pa0 += BKB; pa1 += BKB; pb0 += BKB; pb1 += BKB;
        __syncthreads();

        intx8 af[4], bg[4];
        #pragma unroll
        for (int t = 0; t < 4; ++t) {
            const int4 alo = *(const int4*)(As + aoff[t]);
            const int4 ahi = *(const int4*)(As + (aoff[t] ^ 16));
            af[t] = intx8{alo.x, alo.y, alo.z, alo.w, ahi.x, ahi.y, ahi.z, ahi.w};
            const int4 blo = *(const int4*)(Bs + boff[t]);
            const int4 bhi = *(const int4*)(Bs + (boff[t] ^ 16));
            bg[t] = intx8{blo.x, blo.y, blo.z, blo.w, bhi.x, bhi.y, bhi.z, bhi.w};
        }

        #pragma unroll
        for (int tm = 0; tm < 4; ++tm)
            #pragma unroll
            for (int tn = 0; tn < 4; ++tn)
                acc[tm][tn] = __builtin_amdgcn_mfma_scale_f32_16x16x128_f8f6f4(
                    af[tm], bg[tn], acc[tm][tn],
                    0, 0,          // cbsz = fp8 e4m3, blgp = fp8 e4m3
                    0, 127,        // A scale: opsel 0, E8M0 127 = 1.0
                    0, 127);       // B scale: 1.0
        __syncthreads();
    }

    // ---- epilogue: scale, capture diag, exp in place ----
    const int growb = bm * BM + wrow;
    const int gcolb = bn * BN + wcol;

    #pragma unroll
    for (int tm = 0; tm < 4; ++tm)
        #pragma unroll
        for (int tn = 0; tn < 4; ++tn)
            #pragma unroll
            for (int r = 0; r < 4; ++r) {
                const float l = acc[tm][tn][r] * scale;
                const int grow = growb + tm * 16 + quad * 4 + r;
                const int gcol = gcolb + tn * 16 + lanelo;
                if (grow == gcol) diag[grow] = l;
                acc[tm][tn][r] = __expf(l);
            }

    // ---- row sums: reduce over the 16 lanes sharing a row, then atomicAdd ----
    #pragma unroll
    for (int tm = 0; tm < 4; ++tm) {
        floatx4 rs = acc[tm][0] + acc[tm][1] + acc[tm][2] + acc[tm][3];
        #pragma unroll
        for (int r = 0; r < 4; ++r) {
            float v = rs[r];
            v += __shfl_xor(v, 1);
            v += __shfl_xor(v, 2);
            v += __shfl_xor(v, 4);
            v += __shfl_xor(v, 8);
            if (lanelo == 0)
                atomicAdd(&rowsum[growb + tm * 16 + quad * 4 + r], v);
        }
    }

    // ---- col sums: reduce over quads (xor 16, 32), then atomicAdd ----
    #pragma unroll
    for (int tn = 0; tn < 4; ++tn) {
        float cs = 0.f;
        #pragma unroll
        for (int tm = 0; tm < 4; ++tm)
            cs += acc[tm][tn][0] + acc[tm][tn][1] + acc[tm][tn][2] + acc[tm][tn][3];
        cs += __shfl_xor(cs, 16);
        cs += __shfl_xor(cs, 32);
        if (quad == 0)
            atomicAdd(&colsum[gcolb + tn * 16 + lanelo], cs);
    }
}

// ---- Kernel 3: loss = mean( 0.5*(log(rowsum)+log(colsum)) - diag ) ---------
// out zeroed by normalize_fp8 (stream-ordered before this kernel).
__global__ __launch_bounds__(256)
void final_reduce(const float* __restrict__ rowsum, const float* __restrict__ colsum,
                  const float* __restrict__ diag, float* __restrict__ out, int n) {
    const int i = blockIdx.x * 256 + threadIdx.x;
    const int t = threadIdx.x;
    float v = 0.5f * (logf(rowsum[i]) + logf(colsum[i])) - diag[i];
    #pragma unroll
    for (int o = 1; o < 64; o <<= 1) v += __shfl_xor(v, o);
    __shared__ float ws[4];
    if ((t & 63) == 0) ws[t >> 6] = v;
    __syncthreads();
    if (t == 0) atomicAdd(out, (ws[0] + ws[1] + ws[2] + ws[3]) / (float)n);
}

extern "C" void kernel_launch(void* const* d_in, const int* in_sizes, int n_in,
                              void* d_out, int out_size, void* d_ws, size_t ws_size,
                              hipStream_t stream) {
    const float* img = (const float*)d_in[0];
    const float* txt = (const float*)d_in[1];
    float* out = (float*)d_out;

    const int D = 1024;
    const int N = in_sizes[0] / D;   // 8192

    unsigned char* imgq = (unsigned char*)d_ws;
    unsigned char* txtq = imgq + (size_t)N * D;
    float* rowsum = (float*)(txtq + (size_t)N * D);   // rowsum[N] ++ colsum[N]
    float* colsum = rowsum + N;
    float* diag = colsum + N;

    normalize_fp8<<<2 * N / 4, 256, 0, stream>>>(img, txt, (unsigned int*)imgq,
                                                 (unsigned int*)txtq, rowsum, out, N);

    dim3 grid(N / BM, N / BN);
    // acc = sum of (16a)(16b) = 256*cos; scale undoes 256 and applies 1/T.
    gemm_exp_kernel<<<grid, 256, 0, stream>>>(imgq, txtq, rowsum, colsum, diag,
                                              D, 1.0f / (256.0f * 0.07f));
    final_reduce<<<N / 256, 256, 0, stream>>>(rowsum, colsum, diag, out, N);
}